// Round 7
// baseline (873.922 us; speedup 1.0000x reference)
//
#include <hip/hip_runtime.h>
#include <hip/hip_bf16.h>
#include <math.h>

typedef __hip_bfloat16 bf16;

#define FEAT 128
#define NRBF 20
#define CUTOFF_F 5.0f
#define KSCALE 0.62831853071795864769f  // pi / 5

__device__ __forceinline__ float b2f(bf16 x) { return __bfloat162float(x); }
__device__ __forceinline__ bf16 f2b(float x) { return __float2bfloat16(x); }

template<int F32>
__device__ __forceinline__ float LD(const void* p, size_t i) {
    if (F32) return ((const float*)p)[i];
    return b2f(((const bf16*)p)[i]);
}
template<int F32>
__device__ __forceinline__ void ST(void* p, size_t i, float v) {
    if (F32) ((float*)p)[i] = v;
    else ((bf16*)p)[i] = f2b(v);
}

__device__ __forceinline__ int get_dst(const int* nb, int e, int is64) {
    return is64 ? nb[4 * e] : nb[2 * e];
}
__device__ __forceinline__ int get_src(const int* nb, int e, int is64) {
    return is64 ? nb[4 * e + 2] : nb[2 * e + 1];
}
__device__ __forceinline__ int clampi(int v, int n) {
    return v < 0 ? 0 : (v >= n ? n - 1 : v);
}

// ---------- init: zero counts + sniff dtypes ----------
__global__ void init_kernel(const void* __restrict__ s_ptr, const int* __restrict__ nbrs32,
                            int nE, int* __restrict__ flags, int* __restrict__ counts, int nN) {
    int t = blockIdx.x * blockDim.x + threadIdx.x;
    if (t < nN) counts[t] = 0;
    if (t == 0) {
        const unsigned* u = (const unsigned*)s_ptr;
        int hits = 0;
        for (int i = 0; i < 64; ++i) {
            unsigned ef = (u[i] >> 7) & 0xFF;
            hits += (ef >= 110 && ef <= 135) ? 1 : 0;
        }
        flags[0] = (hits < 32) ? 1 : 0;   // 1 => f32 inputs
        int lim = 2 * nE; if (lim > 128) lim = 128;
        int allz = 1;
        for (int i = 1; i < lim; i += 2) allz &= (nbrs32[i] == 0);
        flags[1] = allz;                   // 1 => int64 nbrs
    }
}

// ---------- CSR build ----------
__global__ void hist_kernel(const int* __restrict__ nbrs, const int* __restrict__ flags,
                            int* __restrict__ counts, int nE, int nN) {
    int e = blockIdx.x * blockDim.x + threadIdx.x;
    if (e < nE) {
        int d = clampi(get_dst(nbrs, e, flags[1]), nN);
        atomicAdd(&counts[d], 1);
    }
}

__global__ __launch_bounds__(1024) void scan_kernel(const int* __restrict__ counts,
        int* __restrict__ offsets, int* __restrict__ cursor, int nN) {
    __shared__ int part[1024];
    const int t = threadIdx.x;
    const int chunk = (nN + 1023) / 1024;
    const int base = t * chunk;
    int local[32];
    int sum = 0;
    for (int c = 0; c < chunk && c < 32; ++c) {
        int idx = base + c;
        int v = (idx < nN) ? counts[idx] : 0;
        local[c] = v;
        sum += v;
    }
    part[t] = sum;
    __syncthreads();
    for (int off = 1; off < 1024; off <<= 1) {
        int add = (t >= off) ? part[t - off] : 0;
        __syncthreads();
        part[t] += add;
        __syncthreads();
    }
    int run = part[t] - sum;
    for (int c = 0; c < chunk && c < 32; ++c) {
        int idx = base + c;
        if (idx < nN) { offsets[idx] = run; cursor[idx] = run; run += local[c]; }
    }
    if (t == 1023) offsets[nN] = part[1023];
}

// ---------- prep: WdT[c][k] = Wd[k][c] (f32), bdT[c] = bd[c] (f32) ----------
__global__ __launch_bounds__(384) void prep_kernel(const void* __restrict__ Wd,
        const void* __restrict__ bd, float* __restrict__ WdT, float* __restrict__ bdT,
        const int* __restrict__ flags) {
    const int c = threadIdx.x;
    if (flags[0]) {
        for (int k = 0; k < NRBF; ++k) WdT[c * NRBF + k] = ((const float*)Wd)[k * 384 + c];
        bdT[c] = ((const float*)bd)[c];
    } else {
        for (int k = 0; k < NRBF; ++k) WdT[c * NRBF + k] = b2f(((const bf16*)Wd)[k * 384 + c]);
        bdT[c] = b2f(((const bf16*)bd)[c]);
    }
}

// ---------- scatter (4B only) + coalesced e-indexed side records ----------
// edge_ids[pos]=e (scatter); src_e[e]=j, u_env_e[e]={ux,uy,uz,env}, g_e[e][20] (coalesced)
template<int F32>
__device__ void pre_scatter_body(const void* __restrict__ r_ij, const int* __restrict__ nbrs,
        int is64, int* __restrict__ cursor, int* __restrict__ edge_ids,
        int* __restrict__ src_e, float4* __restrict__ u_env_e, float* __restrict__ g_e,
        int e, int nE, int nN) {
    const int d = clampi(get_dst(nbrs, e, is64), nN);
    const int j = clampi(get_src(nbrs, e, is64), nN);
    int pos = atomicAdd(&cursor[d], 1);
    pos = clampi(pos, nE);
    edge_ids[pos] = e;
    src_e[e] = j;

    const float rx = LD<F32>(r_ij, (size_t)3 * e + 0);
    const float ry = LD<F32>(r_ij, (size_t)3 * e + 1);
    const float rz = LD<F32>(r_ij, (size_t)3 * e + 2);
    const float d2   = rx * rx + ry * ry + rz * rz + 3e-15f;
    const float invd = rsqrtf(d2);
    const float dd   = d2 * invd;
    const float x  = dd * KSCALE;
    const float s1 = F32 ? sinf(x) : __sinf(x);
    const float c1 = F32 ? cosf(x) : __cosf(x);
    const float env = (dd < CUTOFF_F) ? (0.5f * (c1 + 1.0f)) : 0.0f;
    u_env_e[e] = make_float4(rx * invd, ry * invd, rz * invd, env);

    const float scale = invd * env;
    const float tc = 2.0f * c1;
    float skm2 = 0.f, skm1 = s1;
    float* g = g_e + (size_t)e * NRBF;
    g[0] = s1 * scale;
    #pragma unroll
    for (int k = 1; k < NRBF; ++k) {
        const float sk = fmaf(tc, skm1, -skm2);
        g[k] = sk * scale;
        skm2 = skm1; skm1 = sk;
    }
}

__global__ __launch_bounds__(256) void pre_scatter_kernel(const void* r_ij, const int* nbrs,
        const int* __restrict__ flags, int* cursor, int* edge_ids, int* src_e,
        float4* u_env_e, float* g_e, int nE, int nN) {
    int e = blockIdx.x * blockDim.x + threadIdx.x;
    if (e >= nE) return;
    if (flags[0]) pre_scatter_body<1>(r_ij, nbrs, flags[1], cursor, edge_ids, src_e, u_env_e, g_e, e, nE, nN);
    else          pre_scatter_body<0>(r_ij, nbrs, flags[1], cursor, edge_ids, src_e, u_env_e, g_e, e, nE, nN);
}

// ---------- fused node MLP: phi = silu(s@W1+b1)@W2 + b2 (phi bf16) ----------
template<int F32>
__device__ void gemm_body(const void* __restrict__ s_j, const void* __restrict__ W1,
                          const void* __restrict__ b1, const void* __restrict__ W2,
                          const void* __restrict__ b2v, bf16* __restrict__ phi, int nN) {
    __shared__ float sl[8][FEAT];
    __shared__ float hl[8][FEAT];
    const int t = threadIdx.x;
    const int n0 = blockIdx.x * 8;
    for (int idx = t; idx < 8 * FEAT; idx += 384) {
        int n = idx >> 7, k = idx & 127;
        int row = n0 + n;
        sl[n][k] = (row < nN) ? LD<F32>(s_j, (size_t)row * FEAT + k) : 0.f;
    }
    __syncthreads();
    for (int idx = t; idx < 8 * FEAT; idx += 384) {
        int n = idx >> 7, f = idx & 127;
        float a = 0.f;
        #pragma unroll 4
        for (int k = 0; k < FEAT; ++k) a = fmaf(sl[n][k], LD<F32>(W1, (size_t)k * FEAT + f), a);
        a += LD<F32>(b1, f);
        float sg = F32 ? (1.0f / (1.0f + expf(-a))) : (1.0f / (1.0f + __expf(-a)));
        hl[n][f] = a * sg;
    }
    __syncthreads();
    float acc[8] = {};
    #pragma unroll 4
    for (int k = 0; k < FEAT; ++k) {
        const float w = LD<F32>(W2, (size_t)k * 384 + t);
        #pragma unroll
        for (int n = 0; n < 8; ++n) acc[n] = fmaf(hl[n][k], w, acc[n]);
    }
    const float bb = LD<F32>(b2v, t);
    #pragma unroll
    for (int n = 0; n < 8; ++n) {
        int row = n0 + n;
        if (row < nN) phi[(size_t)row * 384 + t] = f2b(acc[n] + bb);
    }
}

__global__ __launch_bounds__(384) void gemm_node_kernel(const void* s_j, const void* W1,
        const void* b1, const void* W2, const void* b2v, bf16* phi,
        const int* __restrict__ flags, int nN) {
    if (flags[0]) gemm_body<1>(s_j, W1, b1, W2, b2v, phi, nN);
    else          gemm_body<0>(s_j, W1, b1, W2, b2v, phi, nN);
}

// ---------- message: one block per node, one THREAD per channel ----------
// waves 0-1 (ch 0..127): i0 = w*phi, accumulate i0*v_j      -> dv part A
// waves 2-3 (ch 128..255): ds += w*phi
// waves 4-5 (ch 256..383): i2 = w*phi, accumulate i2*u      -> dv part C (via LDS)
template<int F32>
__device__ void msg_body(const bf16* __restrict__ phi, const void* __restrict__ v_j,
        const float* __restrict__ WdT, const float* __restrict__ bdT,
        const int* __restrict__ offsets, const int* __restrict__ edge_ids,
        const int* __restrict__ src_e, const float4* __restrict__ u_env_e,
        const float* __restrict__ g_e, void* __restrict__ out, int nE, int nN) {
    const int i = blockIdx.x;
    const int t = threadIdx.x;
    const int grp = t >> 7;        // wave-uniform (wave w: grp = (64w)>>7)
    const int f = t & 127;

    float wd[NRBF];
    #pragma unroll
    for (int k = 0; k < NRBF; ++k) wd[k] = WdT[(size_t)t * NRBF + k];
    const float bdv = bdT[t];

    int start = offsets[i];
    int end   = offsets[i + 1];
    if (start < 0) start = 0;
    if (end > nE) end = nE;

    float a0 = 0.f, a1 = 0.f, a2 = 0.f;

    #pragma unroll 2
    for (int p = start; p < end; ++p) {
        const int e = clampi(edge_ids[p], nE);      // uniform -> s_load
        const int j = clampi(src_e[e], nN);         // uniform -> s_load
        const float4 ue = u_env_e[e];               // uniform -> s_load_dwordx4
        const float* g = g_e + (size_t)e * NRBF;    // uniform -> 5x s_load_dwordx4

        float w = bdv * ue.w;
        #pragma unroll
        for (int k = 0; k < NRBF; ++k) w = fmaf(g[k], wd[k], w);

        const float ph = b2f(phi[(size_t)j * 384 + t]);
        const float im = w * ph;

        if (grp == 0) {
            const size_t vb = ((size_t)j * FEAT + f) * 3;
            const float vx = LD<F32>(v_j, vb + 0);
            const float vy = LD<F32>(v_j, vb + 1);
            const float vz = LD<F32>(v_j, vb + 2);
            a0 = fmaf(im, vx, a0);
            a1 = fmaf(im, vy, a1);
            a2 = fmaf(im, vz, a2);
        } else if (grp == 1) {
            a0 += im;
        } else {
            a0 = fmaf(im, ue.x, a0);
            a1 = fmaf(im, ue.y, a1);
            a2 = fmaf(im, ue.z, a2);
        }
    }

    __shared__ float dc[FEAT][3];
    if (grp == 2) { dc[f][0] = a0; dc[f][1] = a1; dc[f][2] = a2; }
    __syncthreads();
    if (grp == 0) {
        const size_t ob = (size_t)nN * FEAT + ((size_t)i * FEAT + f) * 3;
        ST<F32>(out, ob + 0, a0 + dc[f][0]);
        ST<F32>(out, ob + 1, a1 + dc[f][1]);
        ST<F32>(out, ob + 2, a2 + dc[f][2]);
    } else if (grp == 1) {
        ST<F32>(out, (size_t)i * FEAT + f, a0);
    }
}

__global__ __launch_bounds__(384) void msg_kernel(const bf16* phi, const void* v_j,
        const float* WdT, const float* bdT, const int* offsets, const int* edge_ids,
        const int* src_e, const float4* u_env_e, const float* g_e,
        const int* __restrict__ flags, void* out, int nE, int nN) {
    if (flags[0]) msg_body<1>(phi, v_j, WdT, bdT, offsets, edge_ids, src_e, u_env_e, g_e, out, nE, nN);
    else          msg_body<0>(phi, v_j, WdT, bdT, offsets, edge_ids, src_e, u_env_e, g_e, out, nE, nN);
}

extern "C" void kernel_launch(void* const* d_in, const int* in_sizes, int n_in,
                              void* d_out, int out_size, void* d_ws, size_t ws_size,
                              hipStream_t stream) {
    const void* s_j  = d_in[0];
    const void* v_j  = d_in[1];
    const void* r_ij = d_in[2];
    const int*  nbrs = (const int*)d_in[3];
    const void* W1   = d_in[4];
    const void* b1   = d_in[5];
    const void* W2   = d_in[6];
    const void* b2   = d_in[7];
    const void* Wd   = d_in[8];
    const void* bd   = d_in[9];

    const int nN = out_size / (4 * FEAT);   // 20000
    const int nE = in_sizes[2] / 3;         // 640000

    char* ws = (char*)d_ws;
    size_t off = 0;
    auto alloc = [&](size_t bytes) -> void* {
        void* p = ws + off;
        off = (off + bytes + 255) & ~(size_t)255;
        return p;
    };
    int*    flags    = (int*)alloc(16);
    int*    counts   = (int*)alloc((size_t)nN * 4);
    int*    offsets  = (int*)alloc(((size_t)nN + 1) * 4);
    int*    cursor   = (int*)alloc((size_t)nN * 4);
    int*    edge_ids = (int*)alloc((size_t)nE * 4);
    int*    src_e    = (int*)alloc((size_t)nE * 4);
    float4* u_env_e  = (float4*)alloc((size_t)nE * 16);
    float*  g_e      = (float*)alloc((size_t)nE * NRBF * 4);
    float*  WdT      = (float*)alloc((size_t)384 * NRBF * 4);
    float*  bdT      = (float*)alloc((size_t)384 * 4);
    bf16*   phi      = (bf16*)alloc((size_t)nN * 384 * 2);
    (void)ws_size;  // total ~82 MB, same scale as the round-6 mode-B footprint that fit

    init_kernel<<<(nN + 255) / 256, 256, 0, stream>>>(s_j, nbrs, nE, flags, counts, nN);
    hist_kernel<<<(nE + 255) / 256, 256, 0, stream>>>(nbrs, flags, counts, nE, nN);
    scan_kernel<<<1, 1024, 0, stream>>>(counts, offsets, cursor, nN);
    prep_kernel<<<1, 384, 0, stream>>>(Wd, bd, WdT, bdT, flags);

    pre_scatter_kernel<<<(nE + 255) / 256, 256, 0, stream>>>(
        r_ij, nbrs, flags, cursor, edge_ids, src_e, u_env_e, g_e, nE, nN);

    gemm_node_kernel<<<(nN + 7) / 8, 384, 0, stream>>>(s_j, W1, b1, W2, b2, phi, flags, nN);

    msg_kernel<<<nN, 384, 0, stream>>>(phi, v_j, WdT, bdT, offsets, edge_ids,
                                       src_e, u_env_e, g_e, flags, d_out, nE, nN);
}

// Round 8
// 536.246 us; speedup vs baseline: 1.6297x; 1.6297x over previous
//
#include <hip/hip_runtime.h>
#include <hip/hip_bf16.h>
#include <math.h>

typedef __hip_bfloat16 bf16;

#define FEAT 128
#define NRBF 20
#define CUTOFF_F 5.0f
#define KSCALE 0.62831853071795864769f  // pi / 5

__device__ __forceinline__ float b2f(bf16 x) { return __bfloat162float(x); }
__device__ __forceinline__ bf16 f2b(float x) { return __float2bfloat16(x); }

template<int F32>
__device__ __forceinline__ float LD(const void* p, size_t i) {
    if (F32) return ((const float*)p)[i];
    return b2f(((const bf16*)p)[i]);
}
template<int F32>
__device__ __forceinline__ void ST(void* p, size_t i, float v) {
    if (F32) ((float*)p)[i] = v;
    else ((bf16*)p)[i] = f2b(v);
}

__device__ __forceinline__ int get_dst(const int* nb, int e, int is64) {
    return is64 ? nb[4 * e] : nb[2 * e];
}
__device__ __forceinline__ int get_src(const int* nb, int e, int is64) {
    return is64 ? nb[4 * e + 2] : nb[2 * e + 1];
}
__device__ __forceinline__ int clampi(int v, int n) {
    return v < 0 ? 0 : (v >= n ? n - 1 : v);
}

// ---------- init: zero counts + sniff dtypes ----------
__global__ void init_kernel(const void* __restrict__ s_ptr, const int* __restrict__ nbrs32,
                            int nE, int* __restrict__ flags, int* __restrict__ counts, int nN) {
    int t = blockIdx.x * blockDim.x + threadIdx.x;
    if (t < nN) counts[t] = 0;
    if (t == 0) {
        const unsigned* u = (const unsigned*)s_ptr;
        int hits = 0;
        for (int i = 0; i < 64; ++i) {
            unsigned ef = (u[i] >> 7) & 0xFF;
            hits += (ef >= 110 && ef <= 135) ? 1 : 0;
        }
        flags[0] = (hits < 32) ? 1 : 0;   // 1 => f32 inputs
        int lim = 2 * nE; if (lim > 128) lim = 128;
        int allz = 1;
        for (int i = 1; i < lim; i += 2) allz &= (nbrs32[i] == 0);
        flags[1] = allz;                   // 1 => int64 nbrs
    }
}

// ---------- CSR build ----------
__global__ void hist_kernel(const int* __restrict__ nbrs, const int* __restrict__ flags,
                            int* __restrict__ counts, int nE, int nN) {
    int e = blockIdx.x * blockDim.x + threadIdx.x;
    if (e < nE) {
        int d = clampi(get_dst(nbrs, e, flags[1]), nN);
        atomicAdd(&counts[d], 1);
    }
}

__global__ __launch_bounds__(1024) void scan_kernel(const int* __restrict__ counts,
        int* __restrict__ offsets, int* __restrict__ cursor, int nN) {
    __shared__ int part[1024];
    const int t = threadIdx.x;
    const int chunk = (nN + 1023) / 1024;
    const int base = t * chunk;
    int local[32];
    int sum = 0;
    for (int c = 0; c < chunk && c < 32; ++c) {
        int idx = base + c;
        int v = (idx < nN) ? counts[idx] : 0;
        local[c] = v;
        sum += v;
    }
    part[t] = sum;
    __syncthreads();
    for (int off = 1; off < 1024; off <<= 1) {
        int add = (t >= off) ? part[t - off] : 0;
        __syncthreads();
        part[t] += add;
        __syncthreads();
    }
    int run = part[t] - sum;
    for (int c = 0; c < chunk && c < 32; ++c) {
        int idx = base + c;
        if (idx < nN) { offsets[idx] = run; cursor[idx] = run; run += local[c]; }
    }
    if (t == 1023) offsets[nN] = part[1023];
}

// ---------- prep: WdT[c][k] = Wd[k][c] (f32, 20 per channel), bdT[c] ----------
__global__ __launch_bounds__(384) void prep_kernel(const void* __restrict__ Wd,
        const void* __restrict__ bd, float* __restrict__ WdT, float* __restrict__ bdT,
        const int* __restrict__ flags) {
    const int c = threadIdx.x;
    if (flags[0]) {
        for (int k = 0; k < NRBF; ++k) WdT[c * NRBF + k] = ((const float*)Wd)[k * 384 + c];
        bdT[c] = ((const float*)bd)[c];
    } else {
        for (int k = 0; k < NRBF; ++k) WdT[c * NRBF + k] = b2f(((const bf16*)Wd)[k * 384 + c]);
        bdT[c] = b2f(((const bf16*)bd)[c]);
    }
}

// ---------- scatter + POSITION-indexed side records (round-6 msg_b layout) ----------
// src_ids[pos]=j, u_env[pos]={ux,uy,uz,env}, gbuf[pos*20+k]
template<int F32>
__device__ void pre_scatter_body(const void* __restrict__ r_ij, const int* __restrict__ nbrs,
        int is64, int* __restrict__ cursor, int* __restrict__ src_ids,
        float4* __restrict__ u_env, float* __restrict__ gbuf, int e, int nE, int nN) {
    const int d = clampi(get_dst(nbrs, e, is64), nN);
    const int j = clampi(get_src(nbrs, e, is64), nN);
    int pos = atomicAdd(&cursor[d], 1);
    pos = clampi(pos, nE);
    src_ids[pos] = j;

    const float rx = LD<F32>(r_ij, (size_t)3 * e + 0);
    const float ry = LD<F32>(r_ij, (size_t)3 * e + 1);
    const float rz = LD<F32>(r_ij, (size_t)3 * e + 2);
    const float d2   = rx * rx + ry * ry + rz * rz + 3e-15f;
    const float invd = rsqrtf(d2);
    const float dd   = d2 * invd;
    const float x  = dd * KSCALE;
    const float s1 = F32 ? sinf(x) : __sinf(x);
    const float c1 = F32 ? cosf(x) : __cosf(x);
    const float env = (dd < CUTOFF_F) ? (0.5f * (c1 + 1.0f)) : 0.0f;
    u_env[pos] = make_float4(rx * invd, ry * invd, rz * invd, env);

    const float scale = invd * env;
    const float tc = 2.0f * c1;
    float skm2 = 0.f, skm1 = s1;
    float* g = gbuf + (size_t)pos * NRBF;
    g[0] = s1 * scale;
    #pragma unroll
    for (int k = 1; k < NRBF; ++k) {
        const float sk = fmaf(tc, skm1, -skm2);
        g[k] = sk * scale;
        skm2 = skm1; skm1 = sk;
    }
}

__global__ __launch_bounds__(256) void pre_scatter_kernel(const void* r_ij, const int* nbrs,
        const int* __restrict__ flags, int* cursor, int* src_ids, float4* u_env,
        float* gbuf, int nE, int nN) {
    int e = blockIdx.x * blockDim.x + threadIdx.x;
    if (e >= nE) return;
    if (flags[0]) pre_scatter_body<1>(r_ij, nbrs, flags[1], cursor, src_ids, u_env, gbuf, e, nE, nN);
    else          pre_scatter_body<0>(r_ij, nbrs, flags[1], cursor, src_ids, u_env, gbuf, e, nE, nN);
}

// ---------- fused node MLP: phi = silu(s@W1+b1)@W2 + b2 (phi bf16) ----------
template<int F32>
__device__ void gemm_body(const void* __restrict__ s_j, const void* __restrict__ W1,
                          const void* __restrict__ b1, const void* __restrict__ W2,
                          const void* __restrict__ b2v, bf16* __restrict__ phi, int nN) {
    __shared__ float sl[8][FEAT];
    __shared__ float hl[8][FEAT];
    const int t = threadIdx.x;
    const int n0 = blockIdx.x * 8;
    for (int idx = t; idx < 8 * FEAT; idx += 384) {
        int n = idx >> 7, k = idx & 127;
        int row = n0 + n;
        sl[n][k] = (row < nN) ? LD<F32>(s_j, (size_t)row * FEAT + k) : 0.f;
    }
    __syncthreads();
    for (int idx = t; idx < 8 * FEAT; idx += 384) {
        int n = idx >> 7, f = idx & 127;
        float a = 0.f;
        #pragma unroll 4
        for (int k = 0; k < FEAT; ++k) a = fmaf(sl[n][k], LD<F32>(W1, (size_t)k * FEAT + f), a);
        a += LD<F32>(b1, f);
        float sg = F32 ? (1.0f / (1.0f + expf(-a))) : (1.0f / (1.0f + __expf(-a)));
        hl[n][f] = a * sg;
    }
    __syncthreads();
    float acc[8] = {};
    #pragma unroll 4
    for (int k = 0; k < FEAT; ++k) {
        const float w = LD<F32>(W2, (size_t)k * 384 + t);
        #pragma unroll
        for (int n = 0; n < 8; ++n) acc[n] = fmaf(hl[n][k], w, acc[n]);
    }
    const float bb = LD<F32>(b2v, t);
    #pragma unroll
    for (int n = 0; n < 8; ++n) {
        int row = n0 + n;
        if (row < nN) phi[(size_t)row * 384 + t] = f2b(acc[n] + bb);
    }
}

__global__ __launch_bounds__(384) void gemm_node_kernel(const void* s_j, const void* W1,
        const void* b1, const void* W2, const void* b2v, bf16* phi,
        const int* __restrict__ flags, int nN) {
    if (flags[0]) gemm_body<1>(s_j, W1, b1, W2, b2v, phi, nN);
    else          gemm_body<0>(s_j, W1, b1, W2, b2v, phi, nN);
}

// ---------- message: block=node, 128 threads, 3 channels/thread, f32 wd ----------
template<int F32>
__device__ void msg_body(const void* __restrict__ v_j, const float* __restrict__ WdT,
        const float* __restrict__ bdT, const bf16* __restrict__ phi,
        const float* __restrict__ gbuf, const int* __restrict__ src_ids,
        const float4* __restrict__ u_env, const int* __restrict__ offsets,
        void* __restrict__ out, int nE, int nN) {
    const int i = blockIdx.x;
    const int f = threadIdx.x;

    // 60 f32 wd values, float4-loaded from the f32 transpose — no bf16 packing
    // possible, so the allocator must keep them in VGPRs (or spill visibly).
    float wd0[NRBF], wd1[NRBF], wd2[NRBF];
    {
        const float4* w4a = (const float4*)(WdT + (size_t)f * NRBF);
        const float4* w4b = (const float4*)(WdT + (size_t)(FEAT + f) * NRBF);
        const float4* w4c = (const float4*)(WdT + (size_t)(2 * FEAT + f) * NRBF);
        #pragma unroll
        for (int q = 0; q < 5; ++q) {
            float4 a = w4a[q], b = w4b[q], c = w4c[q];
            wd0[4 * q + 0] = a.x; wd0[4 * q + 1] = a.y; wd0[4 * q + 2] = a.z; wd0[4 * q + 3] = a.w;
            wd1[4 * q + 0] = b.x; wd1[4 * q + 1] = b.y; wd1[4 * q + 2] = b.z; wd1[4 * q + 3] = b.w;
            wd2[4 * q + 0] = c.x; wd2[4 * q + 1] = c.y; wd2[4 * q + 2] = c.z; wd2[4 * q + 3] = c.w;
        }
    }
    const float bd0 = bdT[f];
    const float bd1 = bdT[FEAT + f];
    const float bd2 = bdT[2 * FEAT + f];

    int start = offsets[i];
    int end   = offsets[i + 1];
    if (start < 0) start = 0;
    if (end > nE) end = nE;

    float ds = 0.f, dv0 = 0.f, dv1 = 0.f, dv2 = 0.f;

    for (int p = start; p < end; ++p) {
        const int j = src_ids[p];                 // sequential -> s_load
        const float4 ue = u_env[p];               // sequential -> s_load_dwordx4
        const float* g = gbuf + (size_t)p * NRBF; // sequential -> s_loads
        float t0 = 0.f, t1 = 0.f, t2 = 0.f;
        #pragma unroll
        for (int k = 0; k < NRBF; ++k) {
            const float gk = g[k];
            t0 = fmaf(gk, wd0[k], t0);
            t1 = fmaf(gk, wd1[k], t1);
            t2 = fmaf(gk, wd2[k], t2);
        }
        const float w0 = fmaf(bd0, ue.w, t0);
        const float w1 = fmaf(bd1, ue.w, t1);
        const float w2 = fmaf(bd2, ue.w, t2);

        const bf16* ph = phi + (size_t)j * 384;
        const float p0 = b2f(ph[f]);
        const float p1 = b2f(ph[FEAT + f]);
        const float p2 = b2f(ph[2 * FEAT + f]);
        const float vx = LD<F32>(v_j, ((size_t)j * FEAT + f) * 3 + 0);
        const float vy = LD<F32>(v_j, ((size_t)j * FEAT + f) * 3 + 1);
        const float vz = LD<F32>(v_j, ((size_t)j * FEAT + f) * 3 + 2);

        const float i0 = w0 * p0;
        const float i1 = w1 * p1;
        const float i2 = w2 * p2;
        ds += i1;
        dv0 = fmaf(i2, ue.x, fmaf(i0, vx, dv0));
        dv1 = fmaf(i2, ue.y, fmaf(i0, vy, dv1));
        dv2 = fmaf(i2, ue.z, fmaf(i0, vz, dv2));
    }

    ST<F32>(out, (size_t)i * FEAT + f, ds);
    const size_t ob = (size_t)nN * FEAT + ((size_t)i * FEAT + f) * 3;
    ST<F32>(out, ob + 0, dv0);
    ST<F32>(out, ob + 1, dv1);
    ST<F32>(out, ob + 2, dv2);
}

__global__ __launch_bounds__(128) void msg_kernel(const void* v_j, const float* WdT,
        const float* bdT, const bf16* phi, const float* gbuf, const int* src_ids,
        const float4* u_env, const int* offsets, const int* __restrict__ flags,
        void* out, int nE, int nN) {
    if (flags[0]) msg_body<1>(v_j, WdT, bdT, phi, gbuf, src_ids, u_env, offsets, out, nE, nN);
    else          msg_body<0>(v_j, WdT, bdT, phi, gbuf, src_ids, u_env, offsets, out, nE, nN);
}

extern "C" void kernel_launch(void* const* d_in, const int* in_sizes, int n_in,
                              void* d_out, int out_size, void* d_ws, size_t ws_size,
                              hipStream_t stream) {
    const void* s_j  = d_in[0];
    const void* v_j  = d_in[1];
    const void* r_ij = d_in[2];
    const int*  nbrs = (const int*)d_in[3];
    const void* W1   = d_in[4];
    const void* b1   = d_in[5];
    const void* W2   = d_in[6];
    const void* b2   = d_in[7];
    const void* Wd   = d_in[8];
    const void* bd   = d_in[9];

    const int nN = out_size / (4 * FEAT);   // 20000
    const int nE = in_sizes[2] / 3;         // 640000

    char* ws = (char*)d_ws;
    size_t off = 0;
    auto alloc = [&](size_t bytes) -> void* {
        void* p = ws + off;
        off = (off + bytes + 255) & ~(size_t)255;
        return p;
    };
    int*    flags    = (int*)alloc(16);
    int*    counts   = (int*)alloc((size_t)nN * 4);
    int*    offsets  = (int*)alloc(((size_t)nN + 1) * 4);
    int*    cursor   = (int*)alloc((size_t)nN * 4);
    int*    src_ids  = (int*)alloc((size_t)nE * 4);
    float4* u_env    = (float4*)alloc((size_t)nE * 16);
    float*  gbuf     = (float*)alloc((size_t)nE * NRBF * 4);
    float*  WdT      = (float*)alloc((size_t)384 * NRBF * 4);
    float*  bdT      = (float*)alloc((size_t)384 * 4);
    bf16*   phi      = (bf16*)alloc((size_t)nN * 384 * 2);
    (void)ws_size;  // ~80 MB, same scale as round 6 (which fit)

    init_kernel<<<(nN + 255) / 256, 256, 0, stream>>>(s_j, nbrs, nE, flags, counts, nN);
    hist_kernel<<<(nE + 255) / 256, 256, 0, stream>>>(nbrs, flags, counts, nE, nN);
    scan_kernel<<<1, 1024, 0, stream>>>(counts, offsets, cursor, nN);
    prep_kernel<<<1, 384, 0, stream>>>(Wd, bd, WdT, bdT, flags);

    pre_scatter_kernel<<<(nE + 255) / 256, 256, 0, stream>>>(
        r_ij, nbrs, flags, cursor, src_ids, u_env, gbuf, nE, nN);

    gemm_node_kernel<<<(nN + 7) / 8, 384, 0, stream>>>(s_j, W1, b1, W2, b2, phi, flags, nN);

    msg_kernel<<<nN, 128, 0, stream>>>(v_j, WdT, bdT, phi, gbuf, src_ids, u_env,
                                       offsets, flags, d_out, nE, nN);
}